// Round 12
// baseline (46.970 us; speedup 1.0000x reference)
//
#include <hip/hip_runtime.h>
#include <hip/hip_bf16.h>

// Problem constants
#define BB 8
#define TT 2048
#define CC 1024
#define HH 64

typedef float f32x4 __attribute__((ext_vector_type(4)));
typedef float f32x16 __attribute__((ext_vector_type(16)));
typedef short s16x8 __attribute__((ext_vector_type(8)));   // 8 bf16 in 4 VGPRs

// fp32 -> bf16 (RNE), pure bit math
static __device__ __forceinline__ unsigned short f2bf(float f) {
    unsigned int u = __float_as_uint(f);
    u = (u + 0x7FFFu + ((u >> 16) & 1u)) >> 16;
    return (unsigned short)u;
}

// pack two f32 -> 2 bf16 in one dword (RNE); dst.lo = src0, dst.hi = src1
static __device__ __forceinline__ unsigned cvt_pk_bf16(float lo, float hi) {
    unsigned r;
    asm("v_cvt_pk_bf16_f32 %0, %1, %2" : "=v"(r) : "v"(lo), "v"(hi));
    return r;
}

// async global->LDS, 16B per lane: writes ldsbase + lane*16 (wave-uniform base)
static __device__ __forceinline__ void gll16(const float* gsrc, void* ldst) {
    __builtin_amdgcn_global_load_lds(
        (const __attribute__((address_space(1))) void*)gsrc,
        (__attribute__((address_space(3))) void*)ldst, 16, 0, 0);
}

// ---------------------------------------------------------------------------
// Kernel 0: pack Wq|Wk|Wv [1024][64] fp32 into MFMA B-fragment order, bf16.
// ---------------------------------------------------------------------------
__global__ __launch_bounds__(256) void wt_kernel(
    const float* __restrict__ Wq, const float* __restrict__ Wk,
    const float* __restrict__ Wv, unsigned short* __restrict__ wTf) {
    const int e8 = blockIdx.x * 256 + threadIdx.x;
    const int lane = e8 & 63;
    const int s = (e8 >> 6) & 31;
    const int n16 = e8 >> 11;        // 0..11
    const int sel = n16 >> 2;
    const float* W = (sel == 0) ? Wq : ((sel == 1) ? Wk : Wv);
    const int h = ((n16 & 3) << 4) + (lane & 15);
    const int cb = s * 32 + ((lane >> 4) << 3);
    s16x8 v;
#pragma unroll
    for (int j = 0; j < 8; ++j) v[j] = (short)f2bf(W[(size_t)(cb + j) * HH + h]);
    *reinterpret_cast<s16x8*>(&wTf[(size_t)e8 * 8]) = v;
}

// ---------------------------------------------------------------------------
// Kernel 1: QKV projection GEMM v7.
// 256 blocks x 8 waves; block = 64 rows. Wave (wm,wn): 32 rows x 48 cols.
// BK=64, 16 chunks, 3 LDS buffers. x staged via global_load_lds into
// FRAGMENT-ordered units (conflict-free b128 reads); counted vmcnt + raw
// s_barrier per chunk so loads stay in flight ACROSS barriers (no vmcnt(0)
// drain). B-reg pipeline 4-set/3-slot-ahead. LDS-image epilogue (coalesced).
// Unit u = ((wm*2+m)*2+kh)*2+t holds, at (u*64+lane)*16:
//   x[rb + wm*32+m*16+(lane&15)][c*64 + kh*32 + (lane>>4)*8 + t*4 .. +3]
// ---------------------------------------------------------------------------
__global__ __launch_bounds__(512, 2) void qkv_kernel(
    const float* __restrict__ x, const unsigned short* __restrict__ wTf,
    unsigned short* __restrict__ Qf, unsigned short* __restrict__ Kf,
    unsigned short* __restrict__ Vf) {
    __shared__ __align__(16) unsigned char smem[49152];   // 3 x 16 KB chunk bufs
    const int tid = threadIdx.x;
    const int wv = tid >> 6, lane = tid & 63;
    const int lo = lane & 15, hi = lane >> 4;
    const int wm = wv >> 2, wn = wv & 3;
    const int rb = blockIdx.x * 64;

    // my two gll units
    const int u0 = 2 * wv, u1 = 2 * wv + 1;
    const float* src0 = x + ((size_t)(rb + (u0 >> 3) * 32 + ((u0 >> 2) & 1) * 16 + lo)) * CC
                          + ((u0 >> 1) & 1) * 32 + hi * 8 + (u0 & 1) * 4;
    const float* src1 = x + ((size_t)(rb + (u1 >> 3) * 32 + ((u1 >> 2) & 1) * 16 + lo)) * CC
                          + ((u1 >> 1) & 1) * 32 + hi * 8 + (u1 & 1) * 4;

    f32x4 acc[2][3];
#pragma unroll
    for (int m = 0; m < 2; ++m)
#pragma unroll
        for (int n = 0; n < 3; ++n) acc[m][n] = (f32x4){0.f, 0.f, 0.f, 0.f};

    // B pipeline: 4 reg sets over 32 slots (slot -> set slot&3), 3-ahead
    s16x8 bv[4][3];
#define BLOAD(SET, SLOT)                                                       \
    {                                                                          \
        _Pragma("unroll")                                                      \
        for (int n = 0; n < 3; ++n)                                            \
            bv[SET][n] = *reinterpret_cast<const s16x8*>(                      \
                &wTf[(((size_t)(wn * 3 + n) * 32 + (SLOT)) * 64 + lane) * 8]); \
    }

    // prologue: chunks 0,1 in flight; B slots 0..2
    gll16(src0, smem + u0 * 1024);
    gll16(src1, smem + u1 * 1024);
    gll16(src0 + 64, smem + 16384 + u0 * 1024);
    gll16(src1 + 64, smem + 16384 + u1 * 1024);
    BLOAD(0, 0) BLOAD(1, 1) BLOAD(2, 2)
    asm volatile("s_waitcnt vmcnt(2)" ::: "memory");   // own chunk-0 glls done
    __builtin_amdgcn_s_barrier();                       // everyone's chunk-0 done

#pragma unroll
    for (int c = 0; c < 16; ++c) {
        // issue chunk c+2 (buf (c+2)%3 was fully read in iter c-1)
        if (c + 2 < 16) {
            unsigned char* d = smem + ((c + 2) % 3) * 16384;
            gll16(src0 + (c + 2) * 64, d + u0 * 1024);
            gll16(src1 + (c + 2) * 64, d + u1 * 1024);
        }
        const unsigned char* base = smem + (c % 3) * 16384;
#pragma unroll
        for (int kh = 0; kh < 2; ++kh) {
            const int slot = 2 * c + kh;
            if (slot + 3 < 32) BLOAD((slot + 3) & 3, slot + 3)
            // A frags m=0,1 from fragment-ordered LDS (conflict-free)
            union { unsigned u[4]; s16x8 v; } a0, a1;
            {
                const int uu = ((wm * 2 + 0) * 2 + kh) * 2;   // t=0
                const f32x4 g0 = *reinterpret_cast<const f32x4*>(base + (uu * 64 + lane) * 16);
                const f32x4 g1 = *reinterpret_cast<const f32x4*>(base + ((uu + 1) * 64 + lane) * 16);
                a0.u[0] = cvt_pk_bf16(g0[0], g0[1]);
                a0.u[1] = cvt_pk_bf16(g0[2], g0[3]);
                a0.u[2] = cvt_pk_bf16(g1[0], g1[1]);
                a0.u[3] = cvt_pk_bf16(g1[2], g1[3]);
            }
            {
                const int uu = ((wm * 2 + 1) * 2 + kh) * 2;   // t=0
                const f32x4 g0 = *reinterpret_cast<const f32x4*>(base + (uu * 64 + lane) * 16);
                const f32x4 g1 = *reinterpret_cast<const f32x4*>(base + ((uu + 1) * 64 + lane) * 16);
                a1.u[0] = cvt_pk_bf16(g0[0], g0[1]);
                a1.u[1] = cvt_pk_bf16(g0[2], g0[3]);
                a1.u[2] = cvt_pk_bf16(g1[0], g1[1]);
                a1.u[3] = cvt_pk_bf16(g1[2], g1[3]);
            }
#pragma unroll
            for (int n = 0; n < 3; ++n) {
                acc[0][n] = __builtin_amdgcn_mfma_f32_16x16x32_bf16(a0.v, bv[slot & 3][n], acc[0][n], 0, 0, 0);
                acc[1][n] = __builtin_amdgcn_mfma_f32_16x16x32_bf16(a1.v, bv[slot & 3][n], acc[1][n], 0, 0, 0);
            }
        }
        // counted wait: own gll(c+1) guaranteed done (>=5 newer ops issued);
        // lgkm drained so next iter's gll can't race this iter's ds_reads.
        asm volatile("s_waitcnt vmcnt(4) lgkmcnt(0)" ::: "memory");
        __builtin_amdgcn_s_barrier();
    }
#undef BLOAD

    // ---- Epilogue: acc -> LDS fragment image -> coalesced stores ----
    unsigned short* fr = reinterpret_cast<unsigned short*>(smem);
    // image: per tile-in-block (0/1): base=tib*6144; Q [0,2048) K [2048,4096) V [4096,6144)
#pragma unroll
    for (int n = 0; n < 3; ++n) {
        const int n16 = wn * 3 + n;
        const int sel = n16 >> 2;
#pragma unroll
        for (int m = 0; m < 2; ++m) {
#pragma unroll
            for (int r = 0; r < 4; ++r) {
                const int row64 = wm * 32 + m * 16 + 4 * hi + r;
                const int tib = row64 >> 5, tok31 = row64 & 31;
                const int ib = tib * 6144;
                const unsigned short bvv = f2bf(acc[m][n][r]);
                if (sel == 0) {
                    const int s = n16, half = (lo >> 3) & 1, j = lo & 7;
                    fr[ib + (s * 64 + half * 32 + tok31) * 8 + j] = bvv;
                } else if (sel == 1) {
                    const int s = n16 - 4, half = (lo >> 3) & 1, j = lo & 7;
                    fr[ib + 2048 + (s * 64 + half * 32 + tok31) * 8 + j] = bvv;
                } else {
                    const int h = (n16 - 8) * 16 + lo;
                    const int mt = h >> 5;
                    const int s2 = tok31 >> 4, hf = (tok31 >> 3) & 1, jj = tok31 & 7;
                    fr[ib + 4096 + ((mt * 2 + s2) * 64 + hf * 32 + (h & 31)) * 8 + jj] = bvv;
                }
            }
        }
    }
    __syncthreads();
    // copy out: 1536 groups x 8 elems (24 KB), fully coalesced 16B stores
    const int b_ = rb >> 11;
    const int tile0 = (rb & (TT - 1)) >> 5;
#pragma unroll
    for (int i = 0; i < 3; ++i) {
        const int g = tid + 512 * i;            // 0..1535
        const int tib = (g >= 768) ? 1 : 0;
        const int rem = g - tib * 768;
        const int buf = rem >> 8;               // 0=Q 1=K 2=V
        const int off = rem & 255;
        const s16x8 val = *reinterpret_cast<const s16x8*>(
            &fr[tib * 6144 + buf * 2048 + off * 8]);
        unsigned short* dst = (buf == 0) ? Qf : ((buf == 1) ? Kf : Vf);
        *reinterpret_cast<s16x8*>(
            &dst[((size_t)b_ * 64 + tile0 + tib) * 2048 + off * 8]) = val;
    }
}

// ---------------------------------------------------------------------------
// Kernel 2: flash attention (round-7 structure, unchanged).
// 512 blocks (8 batch x 64 q-tiles of 32 rows) x 8 waves, kv tiles strided.
// ---------------------------------------------------------------------------
__global__ __launch_bounds__(512, 4) void attn_kernel(
    const unsigned short* __restrict__ Qf, const unsigned short* __restrict__ Kf,
    const unsigned short* __restrict__ Vf, float* __restrict__ out) {
    __shared__ __align__(16) char smem[33792 + 2048];   // 35.8 KB
    float (*OfL)[64][33] = reinterpret_cast<float(*)[64][33]>(smem);   // 4 slots
    float (*Mm)[32] = reinterpret_cast<float(*)[32]>(smem + 33792);
    float (*Ml)[32] = reinterpret_cast<float(*)[32]>(smem + 33792 + 1024);

    const int tid = threadIdx.x;
    const int wv = tid >> 6, lane = tid & 63;
    const int q = lane & 31, half = lane >> 5;
    const int b = blockIdx.x & 7;              // batch -> XCD L2 locality
    const int qt = 63 - (blockIdx.x >> 3);     // largest work first
    const int qbase = qt * 32;
    const float CEXP = 0.125f * 1.44269504f;   // scale * log2(e)

    const unsigned short* qp = &Qf[(((size_t)b * 64 + qt) * 256 + lane) * 8];
    s16x8 qf[4];
#pragma unroll
    for (int s = 0; s < 4; ++s) qf[s] = *reinterpret_cast<const s16x8*>(qp + s * 512);

    f32x16 oA, oB;   // O^T h-blocks [0..31],[32..63]; lane holds col q
#pragma unroll
    for (int r = 0; r < 16; ++r) { oA[r] = 0.f; oB[r] = 0.f; }
    float m = -1e30f, l = 0.f;   // raw-score domain

    for (int t = wv; t <= qt; t += 8) {
        const unsigned short* vp = &Vf[(((size_t)b * 64 + t) * 256 + lane) * 8];
        s16x8 vf[4];
#pragma unroll
        for (int i = 0; i < 4; ++i)
            vf[i] = *reinterpret_cast<const s16x8*>(vp + i * 512);
        const unsigned short* kp = &Kf[(((size_t)b * 64 + t) * 256 + lane) * 8];
        f32x16 sa;
#pragma unroll
        for (int r = 0; r < 16; ++r) sa[r] = 0.f;
#pragma unroll
        for (int s = 0; s < 4; ++s) {
            const s16x8 kf = *reinterpret_cast<const s16x8*>(kp + s * 512);
            sa = __builtin_amdgcn_mfma_f32_32x32x16_bf16(kf, qf[s], sa, 0, 0, 0);
        }
        if (t == qt) {
#pragma unroll
            for (int r = 0; r < 16; ++r) {
                const int key = 4 * half + (r & 3) + 8 * (r >> 2);
                if (key > q) sa[r] = -1e30f;
            }
        }
        float pmax = sa[0];
#pragma unroll
        for (int r = 1; r < 16; ++r) pmax = fmaxf(pmax, sa[r]);
        pmax = fmaxf(pmax, __shfl_xor(pmax, 32));
        if (!__all(pmax <= m + 64.f)) {
            const float mnew = fmaxf(m, pmax);
            const float alpha = exp2f((m - mnew) * CEXP);
            l *= alpha;
#pragma unroll
            for (int r = 0; r < 16; ++r) { oA[r] *= alpha; oB[r] *= alpha; }
            m = mnew;
        }
        float rs = 0.f;
#pragma unroll
        for (int r = 0; r < 16; ++r) {
            const float p = exp2f((sa[r] - m) * CEXP);
            sa[r] = p;
            rs += p;
        }
        l += rs + __shfl_xor(rs, 32);
        unsigned d[8];
#pragma unroll
        for (int i = 0; i < 8; ++i) d[i] = cvt_pk_bf16(sa[2 * i], sa[2 * i + 1]);
        const unsigned snd0 = half ? d[0] : d[2];
        const unsigned snd1 = half ? d[1] : d[3];
        const unsigned snd2 = half ? d[4] : d[6];
        const unsigned snd3 = half ? d[5] : d[7];
        const unsigned rcv0 = __shfl_xor(snd0, 32);
        const unsigned rcv1 = __shfl_xor(snd1, 32);
        const unsigned rcv2 = __shfl_xor(snd2, 32);
        const unsigned rcv3 = __shfl_xor(snd3, 32);
        union { unsigned u[4]; s16x8 v; } f0, f1;
        f0.u[0] = half ? rcv0 : d[0];
        f0.u[1] = half ? rcv1 : d[1];
        f0.u[2] = half ? d[2] : rcv0;
        f0.u[3] = half ? d[3] : rcv1;
        f1.u[0] = half ? rcv2 : d[4];
        f1.u[1] = half ? rcv3 : d[5];
        f1.u[2] = half ? d[6] : rcv2;
        f1.u[3] = half ? d[7] : rcv3;
        oA = __builtin_amdgcn_mfma_f32_32x32x16_bf16(vf[0], f0.v, oA, 0, 0, 0);
        oB = __builtin_amdgcn_mfma_f32_32x32x16_bf16(vf[2], f0.v, oB, 0, 0, 0);
        oA = __builtin_amdgcn_mfma_f32_32x32x16_bf16(vf[1], f1.v, oA, 0, 0, 0);
        oB = __builtin_amdgcn_mfma_f32_32x32x16_bf16(vf[3], f1.v, oB, 0, 0, 0);
    }

    // ---- tree combine of 8 partials ----
#define PUBLISH(slot)                                                      \
    {                                                                      \
        _Pragma("unroll")                                                  \
        for (int r = 0; r < 16; ++r) {                                     \
            const int h0 = (r & 3) + 8 * (r >> 2) + 4 * half;              \
            OfL[slot][h0][q] = oA[r];                                      \
            OfL[slot][h0 + 32][q] = oB[r];                                 \
        }                                                                  \
    }
#define MERGE(slot, srcw)                                                  \
    {                                                                      \
        const float mb = Mm[srcw][q], lb = Ml[srcw][q];                    \
        const float M = fmaxf(m, mb);                                      \
        const float wa = exp2f((m - M) * CEXP);                            \
        const float wb = exp2f((mb - M) * CEXP);                           \
        _Pragma("unroll")                                                  \
        for (int r = 0; r < 16; ++r) {                                     \
            const int h0 = (r & 3) + 8 * (r >> 2) + 4 * half;              \
            oA[r] = oA[r] * wa + OfL[slot][h0][q] * wb;                    \
            oB[r] = oB[r] * wa + OfL[slot][h0 + 32][q] * wb;               \
        }                                                                  \
        l = l * wa + lb * wb;                                              \
        m = M;                                                             \
    }

    if (lane < 32) { Mm[wv][q] = m; Ml[wv][q] = l; }
    if (wv >= 4) PUBLISH(wv - 4);
    __syncthreads();
    if (wv < 4) MERGE(wv, wv + 4);
    __syncthreads();
    if (wv == 2 || wv == 3) {
        PUBLISH(wv - 2);
        if (lane < 32) { Mm[wv][q] = m; Ml[wv][q] = l; }
    }
    __syncthreads();
    if (wv < 2) MERGE(wv, wv + 2);
    __syncthreads();
    if (wv == 1) {
        PUBLISH(1);
        if (lane < 32) { Mm[1][q] = m; Ml[1][q] = l; }
    }
    __syncthreads();
    if (wv == 0) {
        MERGE(1, 1);
        const float inv = 1.f / l;
#pragma unroll
        for (int r = 0; r < 16; ++r) {
            const int h0 = (r & 3) + 8 * (r >> 2) + 4 * half;
            OfL[0][h0][q] = oA[r] * inv;
            OfL[0][h0 + 32][q] = oB[r] * inv;
        }
    }
    __syncthreads();
#pragma unroll
    for (int i = 0; i < 4; ++i) {
        const int idx = tid + 512 * i;
        const int h = idx & 63, q2 = idx >> 6;
        out[((size_t)b * TT + qbase + q2) * HH + h] = OfL[0][h][q2];
    }
#undef PUBLISH
#undef MERGE
}

extern "C" void kernel_launch(void* const* d_in, const int* in_sizes, int n_in,
                              void* d_out, int out_size, void* d_ws, size_t ws_size,
                              hipStream_t stream) {
    (void)in_sizes; (void)n_in; (void)out_size; (void)ws_size;
    const float* x  = (const float*)d_in[0];
    const float* Wq = (const float*)d_in[1];
    const float* Wk = (const float*)d_in[2];
    const float* Wv = (const float*)d_in[3];
    float* out = (float*)d_out;

    char* ws = (char*)d_ws;
    unsigned short* wTf = (unsigned short*)ws;                      // 384 KB
    unsigned short* Qf  = (unsigned short*)(ws + 393216);           // 2 MB
    unsigned short* Kf  = (unsigned short*)(ws + 393216 + 2097152); // 2 MB
    unsigned short* Vf  = (unsigned short*)(ws + 393216 + 4194304); // 2 MB

    wt_kernel<<<96, 256, 0, stream>>>(Wq, Wk, Wv, wTf);
    qkv_kernel<<<256, 512, 0, stream>>>(x, wTf, Qf, Kf, Vf);
    attn_kernel<<<512, 512, 0, stream>>>(Qf, Kf, Vf, out);
}

// Round 13
// 42.353 us; speedup vs baseline: 1.1090x; 1.1090x over previous
//
#include <hip/hip_runtime.h>
#include <hip/hip_bf16.h>

// Problem constants
#define BB 8
#define TT 2048
#define CC 1024
#define HH 64

typedef float f32x4 __attribute__((ext_vector_type(4)));
typedef float f32x16 __attribute__((ext_vector_type(16)));
typedef short s16x8 __attribute__((ext_vector_type(8)));   // 8 bf16 in 4 VGPRs

// fp32 -> bf16 (RNE), pure bit math
static __device__ __forceinline__ unsigned short f2bf(float f) {
    unsigned int u = __float_as_uint(f);
    u = (u + 0x7FFFu + ((u >> 16) & 1u)) >> 16;
    return (unsigned short)u;
}

// pack two f32 -> 2 bf16 in one dword (RNE); dst.lo = src0, dst.hi = src1
static __device__ __forceinline__ unsigned cvt_pk_bf16(float lo, float hi) {
    unsigned r;
    asm("v_cvt_pk_bf16_f32 %0, %1, %2" : "=v"(r) : "v"(lo), "v"(hi));
    return r;
}

// ---------------------------------------------------------------------------
// Kernel 0: pack Wq|Wk|Wv [1024][64] fp32 into MFMA B-fragment order, bf16.
// ---------------------------------------------------------------------------
__global__ __launch_bounds__(256) void wt_kernel(
    const float* __restrict__ Wq, const float* __restrict__ Wk,
    const float* __restrict__ Wv, unsigned short* __restrict__ wTf) {
    const int e8 = blockIdx.x * 256 + threadIdx.x;
    const int lane = e8 & 63;
    const int s = (e8 >> 6) & 31;
    const int n16 = e8 >> 11;        // 0..11
    const int sel = n16 >> 2;
    const float* W = (sel == 0) ? Wq : ((sel == 1) ? Wk : Wv);
    const int h = ((n16 & 3) << 4) + (lane & 15);
    const int cb = s * 32 + ((lane >> 4) << 3);
    s16x8 v;
#pragma unroll
    for (int j = 0; j < 8; ++j) v[j] = (short)f2bf(W[(size_t)(cb + j) * HH + h]);
    *reinterpret_cast<s16x8*>(&wTf[(size_t)e8 * 8]) = v;
}

// ---------------------------------------------------------------------------
// Kernel 1: QKV projection GEMM v9.
// 512 blocks x 4 waves (256 thr); block = 32 rows = ONE attn tile -> 2
// INDEPENDENT blocks/CU (barrier drains of one overlap compute of the other).
// Wave wn: 32 rows (2 M-frags, B reused) x 48 cols. BK=128, 8 chunks, dbuf
// LDS, one barrier/chunk. B pipeline 4-deep, x prefetch 2 chunks ahead with
// wave-contiguous load instructions. LDS-image epilogue (coalesced stores).
// ---------------------------------------------------------------------------
__global__ __launch_bounds__(256, 2) void qkv_kernel(
    const float* __restrict__ x, const unsigned short* __restrict__ wTf,
    unsigned short* __restrict__ Qf, unsigned short* __restrict__ Kf,
    unsigned short* __restrict__ Vf) {
    __shared__ unsigned short xb[2][32 * 128];   // 2 x 8 KB bf16, XOR-swizzled
    const int tid = threadIdx.x;
    const int wn = tid >> 6, lane = tid & 63;
    const int lo = lane & 15, hi = lane >> 4;
    const int rb = blockIdx.x * 32;

    // staging: 4 wave-contiguous units; unit u = tid + 256*i ->
    //   row = u>>5 (0..31), col4 = (u&31)*4  (each instr: 2 rows x 512B/wave)
    const int r0 = tid >> 5;            // row for i=0; i adds 8
    const int c4 = (tid & 31) * 4;
    const float* xsrc = &x[(size_t)(rb + r0) * CC + c4];

    // A-frag read bases: rows lo and 16+lo
    const int ab0 = lo * 128, as0 = (lo & 7) << 3;
    const int ab1 = (16 + lo) * 128;    // (16+lo)&7 == lo&7

    f32x4 acc[2][3];
#pragma unroll
    for (int m = 0; m < 2; ++m)
#pragma unroll
        for (int n = 0; n < 3; ++n) acc[m][n] = (f32x4){0.f, 0.f, 0.f, 0.f};

    // x prefetch, 2 chunks deep (two independent register sets)
    f32x4 pfA[4], pfB[4];
#pragma unroll
    for (int i = 0; i < 4; ++i)
        pfA[i] = *reinterpret_cast<const f32x4*>(xsrc + (size_t)(8 * i) * CC);
#pragma unroll
    for (int i = 0; i < 4; ++i)
        pfB[i] = *reinterpret_cast<const f32x4*>(xsrc + (size_t)(8 * i) * CC + 128);

    // B pipeline: 4 reg sets over 32 slots (slot -> set slot&3), 3-ahead
    s16x8 bv[4][3];
#define BLOAD(SET, SLOT)                                                       \
    {                                                                          \
        _Pragma("unroll")                                                      \
        for (int n = 0; n < 3; ++n)                                            \
            bv[SET][n] = *reinterpret_cast<const s16x8*>(                      \
                &wTf[(((size_t)(wn * 3 + n) * 32 + (SLOT)) * 64 + lane) * 8]); \
    }
    BLOAD(0, 0)
    BLOAD(1, 1)
    BLOAD(2, 2)

#pragma unroll
    for (int c = 0; c < 8; ++c) {
        // write staged chunk c (4 x 8B granules, rows r0+8i)
        unsigned short* wb = xb[c & 1];
        {
            const f32x4* pf = (c & 1) ? pfB : pfA;
#pragma unroll
            for (int i = 0; i < 4; ++i) {
                const int rr = r0 + 8 * i;
                ushort4 g;
                g.x = f2bf(pf[i][0]); g.y = f2bf(pf[i][1]);
                g.z = f2bf(pf[i][2]); g.w = f2bf(pf[i][3]);
                *reinterpret_cast<ushort4*>(&wb[rr * 128 + (c4 ^ ((rr & 7) << 3))]) = g;
            }
        }
        __syncthreads();
        // issue chunk c+2's x loads into the freed pf set (2-deep in flight)
        if (c < 6) {
            if (c & 1) {
#pragma unroll
                for (int i = 0; i < 4; ++i)
                    pfB[i] = *reinterpret_cast<const f32x4*>(
                        xsrc + (size_t)(8 * i) * CC + (c + 2) * 128);
            } else {
#pragma unroll
                for (int i = 0; i < 4; ++i)
                    pfA[i] = *reinterpret_cast<const f32x4*>(
                        xsrc + (size_t)(8 * i) * CC + (c + 2) * 128);
            }
        }
        const unsigned short* base = xb[c & 1];
#pragma unroll
        for (int kh = 0; kh < 4; ++kh) {
            const int slot = c * 4 + kh;
            if (slot + 3 < 32) BLOAD((slot + 3) & 3, slot + 3)
            const s16x8 a0 = *reinterpret_cast<const s16x8*>(
                &base[ab0 + ((kh * 32 + hi * 8) ^ as0)]);
            const s16x8 a1 = *reinterpret_cast<const s16x8*>(
                &base[ab1 + ((kh * 32 + hi * 8) ^ as0)]);
#pragma unroll
            for (int n = 0; n < 3; ++n) {
                acc[0][n] = __builtin_amdgcn_mfma_f32_16x16x32_bf16(a0, bv[slot & 3][n], acc[0][n], 0, 0, 0);
                acc[1][n] = __builtin_amdgcn_mfma_f32_16x16x32_bf16(a1, bv[slot & 3][n], acc[1][n], 0, 0, 0);
            }
        }
        // single barrier/chunk: write at c+2 targets this buffer only after
        // the barrier at c+1 (v6-proven safe: reads are consumed pre-barrier).
    }
#undef BLOAD

    // ---- Epilogue: acc -> LDS fragment image -> coalesced stores ----
    __syncthreads();   // mainloop LDS reads done; reuse xb as image (12 KB)
    unsigned short* fr = reinterpret_cast<unsigned short*>(xb);
    // image: Q [0,2048) K [2048,4096) V [4096,6144) elems
#pragma unroll
    for (int n = 0; n < 3; ++n) {
        const int n16 = wn * 3 + n;
        const int sel = n16 >> 2;
#pragma unroll
        for (int m = 0; m < 2; ++m) {
#pragma unroll
            for (int r = 0; r < 4; ++r) {
                const int tok31 = m * 16 + 4 * hi + r;
                const unsigned short bvv = f2bf(acc[m][n][r]);
                if (sel == 0) {
                    const int s = n16, half = (lo >> 3) & 1, j = lo & 7;
                    fr[(s * 64 + half * 32 + tok31) * 8 + j] = bvv;
                } else if (sel == 1) {
                    const int s = n16 - 4, half = (lo >> 3) & 1, j = lo & 7;
                    fr[2048 + (s * 64 + half * 32 + tok31) * 8 + j] = bvv;
                } else {
                    const int h = (n16 - 8) * 16 + lo;
                    const int mt = h >> 5;
                    const int s2 = tok31 >> 4, hf = (tok31 >> 3) & 1, jj = tok31 & 7;
                    fr[4096 + ((mt * 2 + s2) * 64 + hf * 32 + (h & 31)) * 8 + jj] = bvv;
                }
            }
        }
    }
    __syncthreads();
    // copy out: 768 groups x 8 elems (12 KB), fully coalesced 16B stores
    const int b_ = rb >> 11;
    const int tile = (rb & (TT - 1)) >> 5;
    const size_t tb = ((size_t)b_ * 64 + tile) * 2048;
#pragma unroll
    for (int i = 0; i < 3; ++i) {
        const int g = tid + 256 * i;            // 0..767
        const int buf = g >> 8;                 // 0=Q 1=K 2=V
        const int off = g & 255;
        const s16x8 val = *reinterpret_cast<const s16x8*>(&fr[buf * 2048 + off * 8]);
        unsigned short* dst = (buf == 0) ? Qf : ((buf == 1) ? Kf : Vf);
        *reinterpret_cast<s16x8*>(&dst[tb + off * 8]) = val;
    }
}

// ---------------------------------------------------------------------------
// Kernel 2: flash attention (round-7 structure, unchanged — 42.9us build).
// 512 blocks (8 batch x 64 q-tiles of 32 rows) x 8 waves, kv tiles strided.
// ---------------------------------------------------------------------------
__global__ __launch_bounds__(512, 4) void attn_kernel(
    const unsigned short* __restrict__ Qf, const unsigned short* __restrict__ Kf,
    const unsigned short* __restrict__ Vf, float* __restrict__ out) {
    __shared__ __align__(16) char smem[33792 + 2048];   // 35.8 KB
    float (*OfL)[64][33] = reinterpret_cast<float(*)[64][33]>(smem);   // 4 slots
    float (*Mm)[32] = reinterpret_cast<float(*)[32]>(smem + 33792);
    float (*Ml)[32] = reinterpret_cast<float(*)[32]>(smem + 33792 + 1024);

    const int tid = threadIdx.x;
    const int wv = tid >> 6, lane = tid & 63;
    const int q = lane & 31, half = lane >> 5;
    const int b = blockIdx.x & 7;              // batch -> XCD L2 locality
    const int qt = 63 - (blockIdx.x >> 3);     // largest work first
    const int qbase = qt * 32;
    const float CEXP = 0.125f * 1.44269504f;   // scale * log2(e)

    const unsigned short* qp = &Qf[(((size_t)b * 64 + qt) * 256 + lane) * 8];
    s16x8 qf[4];
#pragma unroll
    for (int s = 0; s < 4; ++s) qf[s] = *reinterpret_cast<const s16x8*>(qp + s * 512);

    f32x16 oA, oB;   // O^T h-blocks [0..31],[32..63]; lane holds col q
#pragma unroll
    for (int r = 0; r < 16; ++r) { oA[r] = 0.f; oB[r] = 0.f; }
    float m = -1e30f, l = 0.f;   // raw-score domain

    for (int t = wv; t <= qt; t += 8) {
        const unsigned short* vp = &Vf[(((size_t)b * 64 + t) * 256 + lane) * 8];
        s16x8 vf[4];
#pragma unroll
        for (int i = 0; i < 4; ++i)
            vf[i] = *reinterpret_cast<const s16x8*>(vp + i * 512);
        const unsigned short* kp = &Kf[(((size_t)b * 64 + t) * 256 + lane) * 8];
        f32x16 sa;
#pragma unroll
        for (int r = 0; r < 16; ++r) sa[r] = 0.f;
#pragma unroll
        for (int s = 0; s < 4; ++s) {
            const s16x8 kf = *reinterpret_cast<const s16x8*>(kp + s * 512);
            sa = __builtin_amdgcn_mfma_f32_32x32x16_bf16(kf, qf[s], sa, 0, 0, 0);
        }
        if (t == qt) {
#pragma unroll
            for (int r = 0; r < 16; ++r) {
                const int key = 4 * half + (r & 3) + 8 * (r >> 2);
                if (key > q) sa[r] = -1e30f;
            }
        }
        float pmax = sa[0];
#pragma unroll
        for (int r = 1; r < 16; ++r) pmax = fmaxf(pmax, sa[r]);
        pmax = fmaxf(pmax, __shfl_xor(pmax, 32));
        if (!__all(pmax <= m + 64.f)) {
            const float mnew = fmaxf(m, pmax);
            const float alpha = exp2f((m - mnew) * CEXP);
            l *= alpha;
#pragma unroll
            for (int r = 0; r < 16; ++r) { oA[r] *= alpha; oB[r] *= alpha; }
            m = mnew;
        }
        float rs = 0.f;
#pragma unroll
        for (int r = 0; r < 16; ++r) {
            const float p = exp2f((sa[r] - m) * CEXP);
            sa[r] = p;
            rs += p;
        }
        l += rs + __shfl_xor(rs, 32);
        unsigned d[8];
#pragma unroll
        for (int i = 0; i < 8; ++i) d[i] = cvt_pk_bf16(sa[2 * i], sa[2 * i + 1]);
        const unsigned snd0 = half ? d[0] : d[2];
        const unsigned snd1 = half ? d[1] : d[3];
        const unsigned snd2 = half ? d[4] : d[6];
        const unsigned snd3 = half ? d[5] : d[7];
        const unsigned rcv0 = __shfl_xor(snd0, 32);
        const unsigned rcv1 = __shfl_xor(snd1, 32);
        const unsigned rcv2 = __shfl_xor(snd2, 32);
        const unsigned rcv3 = __shfl_xor(snd3, 32);
        union { unsigned u[4]; s16x8 v; } f0, f1;
        f0.u[0] = half ? rcv0 : d[0];
        f0.u[1] = half ? rcv1 : d[1];
        f0.u[2] = half ? d[2] : rcv0;
        f0.u[3] = half ? d[3] : rcv1;
        f1.u[0] = half ? rcv2 : d[4];
        f1.u[1] = half ? rcv3 : d[5];
        f1.u[2] = half ? d[6] : rcv2;
        f1.u[3] = half ? d[7] : rcv3;
        oA = __builtin_amdgcn_mfma_f32_32x32x16_bf16(vf[0], f0.v, oA, 0, 0, 0);
        oB = __builtin_amdgcn_mfma_f32_32x32x16_bf16(vf[2], f0.v, oB, 0, 0, 0);
        oA = __builtin_amdgcn_mfma_f32_32x32x16_bf16(vf[1], f1.v, oA, 0, 0, 0);
        oB = __builtin_amdgcn_mfma_f32_32x32x16_bf16(vf[3], f1.v, oB, 0, 0, 0);
    }

    // ---- tree combine of 8 partials ----
#define PUBLISH(slot)                                                      \
    {                                                                      \
        _Pragma("unroll")                                                  \
        for (int r = 0; r < 16; ++r) {                                     \
            const int h0 = (r & 3) + 8 * (r >> 2) + 4 * half;              \
            OfL[slot][h0][q] = oA[r];                                      \
            OfL[slot][h0 + 32][q] = oB[r];                                 \
        }                                                                  \
    }
#define MERGE(slot, srcw)                                                  \
    {                                                                      \
        const float mb = Mm[srcw][q], lb = Ml[srcw][q];                    \
        const float M = fmaxf(m, mb);                                      \
        const float wa = exp2f((m - M) * CEXP);                            \
        const float wb = exp2f((mb - M) * CEXP);                           \
        _Pragma("unroll")                                                  \
        for (int r = 0; r < 16; ++r) {                                     \
            const int h0 = (r & 3) + 8 * (r >> 2) + 4 * half;              \
            oA[r] = oA[r] * wa + OfL[slot][h0][q] * wb;                    \
            oB[r] = oB[r] * wa + OfL[slot][h0 + 32][q] * wb;               \
        }                                                                  \
        l = l * wa + lb * wb;                                              \
        m = M;                                                             \
    }

    if (lane < 32) { Mm[wv][q] = m; Ml[wv][q] = l; }
    if (wv >= 4) PUBLISH(wv - 4);
    __syncthreads();
    if (wv < 4) MERGE(wv, wv + 4);
    __syncthreads();
    if (wv == 2 || wv == 3) {
        PUBLISH(wv - 2);
        if (lane < 32) { Mm[wv][q] = m; Ml[wv][q] = l; }
    }
    __syncthreads();
    if (wv < 2) MERGE(wv, wv + 2);
    __syncthreads();
    if (wv == 1) {
        PUBLISH(1);
        if (lane < 32) { Mm[1][q] = m; Ml[1][q] = l; }
    }
    __syncthreads();
    if (wv == 0) {
        MERGE(1, 1);
        const float inv = 1.f / l;
#pragma unroll
        for (int r = 0; r < 16; ++r) {
            const int h0 = (r & 3) + 8 * (r >> 2) + 4 * half;
            OfL[0][h0][q] = oA[r] * inv;
            OfL[0][h0 + 32][q] = oB[r] * inv;
        }
    }
    __syncthreads();
#pragma unroll
    for (int i = 0; i < 4; ++i) {
        const int idx = tid + 512 * i;
        const int h = idx & 63, q2 = idx >> 6;
        out[((size_t)b * TT + qbase + q2) * HH + h] = OfL[0][h][q2];
    }
#undef PUBLISH
#undef MERGE
}

extern "C" void kernel_launch(void* const* d_in, const int* in_sizes, int n_in,
                              void* d_out, int out_size, void* d_ws, size_t ws_size,
                              hipStream_t stream) {
    (void)in_sizes; (void)n_in; (void)out_size; (void)ws_size;
    const float* x  = (const float*)d_in[0];
    const float* Wq = (const float*)d_in[1];
    const float* Wk = (const float*)d_in[2];
    const float* Wv = (const float*)d_in[3];
    float* out = (float*)d_out;

    char* ws = (char*)d_ws;
    unsigned short* wTf = (unsigned short*)ws;                      // 384 KB
    unsigned short* Qf  = (unsigned short*)(ws + 393216);           // 2 MB
    unsigned short* Kf  = (unsigned short*)(ws + 393216 + 2097152); // 2 MB
    unsigned short* Vf  = (unsigned short*)(ws + 393216 + 4194304); // 2 MB

    wt_kernel<<<96, 256, 0, stream>>>(Wq, Wk, Wv, wTf);
    qkv_kernel<<<512, 256, 0, stream>>>(x, wTf, Qf, Kf, Vf);
    attn_kernel<<<512, 512, 0, stream>>>(Qf, Kf, Vf, out);
}